// Round 7
// baseline (516.216 us; speedup 1.0000x reference)
//
#include <hip/hip_runtime.h>

// Problem shape (fixed by reference setup_inputs): B=4, C=128, H=W=256, fp32.
constexpr int Bx = 4;
constexpr int Cx = 128;
constexpr int Hx = 256;
constexpr int Wx = 256;
constexpr int HWx = Hx * Wx;
constexpr int NCHUNK = 16;          // channel chunks
constexpr int CPT = Cx / NCHUNK;    // 8 channels per thread

// 8B load with only 4B alignment guaranteed (gfx950 handles unaligned dwordx2).
struct f2u { float x, y; } __attribute__((packed, aligned(4)));
__device__ __forceinline__ f2u ld2u(const float* p) {
    return *reinterpret_cast<const f2u*>(p);
}

// ---------------------------------------------------------------------------
// Kernel 1: per-(b,c) instance-norm statistics.
// stats interleaved: stats[2g] = mean, stats[2g+1] = rsqrt(var+eps)
// ---------------------------------------------------------------------------
__global__ __launch_bounds__(512) void in_stats(const float* __restrict__ h,
                                                float* __restrict__ stats) {
    const int g = blockIdx.x;   // b*C + c
    const int t = threadIdx.x;
    const float4* p = reinterpret_cast<const float4*>(h + (size_t)g * HWx);

    float4 s4 = {0.f, 0.f, 0.f, 0.f};
    float4 q4 = {0.f, 0.f, 0.f, 0.f};
    #pragma unroll 4
    for (int i = t; i < HWx / 4; i += 512) {
        float4 v = p[i];
        s4.x += v.x; s4.y += v.y; s4.z += v.z; s4.w += v.w;
        q4.x += v.x * v.x; q4.y += v.y * v.y;
        q4.z += v.z * v.z; q4.w += v.w * v.w;
    }
    float s = (s4.x + s4.y) + (s4.z + s4.w);
    float q = (q4.x + q4.y) + (q4.z + q4.w);

    for (int off = 32; off > 0; off >>= 1) {
        s += __shfl_down(s, off, 64);
        q += __shfl_down(q, off, 64);
    }
    __shared__ float rs[8], rq[8];
    const int wid = t >> 6;
    if ((t & 63) == 0) { rs[wid] = s; rq[wid] = q; }
    __syncthreads();
    if (t == 0) {
        float S = 0.f, Q = 0.f;
        #pragma unroll
        for (int i = 0; i < 8; ++i) { S += rs[i]; Q += rq[i]; }
        const float mean = S * (1.0f / HWx);
        const float var  = Q * (1.0f / HWx) - mean * mean;
        stats[2 * g]     = mean;
        stats[2 * g + 1] = rsqrtf(var + 1e-5f);
    }
}

// ---------------------------------------------------------------------------
// Kernel 2: fused warp(gamma), warp(beta), instance-norm apply, combine.
// MLP-forced structure: ALL loads for all CPT=8 channels are issued in one
// fully-unrolled loop into statically-indexed register arrays (40 loads in
// flight, no loop-carried deps), THEN a separate compute+store loop.
// R6 evidence: source-level 2-stage SWP was sunk by the scheduler (VGPR
// dropped to 24). This version makes sinking impossible without spilling:
// the 72 staged floats ARE the program state. VGPR ~100 expected = proof.
// ---------------------------------------------------------------------------
__global__ __launch_bounds__(256) void fuse_kernel(
    const float* __restrict__ h,
    const float* __restrict__ gamma,
    const float* __restrict__ beta,
    const float* __restrict__ flow,
    const float* __restrict__ mask,
    const float* __restrict__ stats,
    float* __restrict__ out)
{
    constexpr int NWG = NCHUNK * Bx * Hx;            // 16384, %8 == 0
    const int orig = blockIdx.x;
    const int bid  = (orig & 7) * (NWG / 8) + (orig >> 3);  // bijective XCD swizzle

    const int chunk = bid >> 10;        // / (Bx*Hx)
    const int rem   = bid & 1023;
    const int b     = rem >> 8;
    const int y     = rem & (Hx - 1);
    const int x     = threadIdx.x;
    const int pix   = (y << 8) | x;

    const float fx = flow[(size_t)b * 2 * HWx + pix];
    const float fy = flow[(size_t)b * 2 * HWx + HWx + pix];
    const float m  = mask[(size_t)b * HWx + pix];

    // Replicate the reference arithmetic exactly (order + divisions):
    const float xs = (float)x / 255.0f;
    const float ys = (float)y / 255.0f;
    const float sx = 2.0f * xs - 1.0f + 2.0f * fx / 256.0f;
    const float sy = 2.0f * ys - 1.0f + 2.0f * fy / 256.0f;
    const float ix = (sx + 1.0f) * 0.5f * 255.0f;
    const float iy = (sy + 1.0f) * 0.5f * 255.0f;

    const float x0f = floorf(ix);
    const float y0f = floorf(iy);
    const float wx1 = ix - x0f;
    const float wy1 = iy - y0f;
    const int x0 = (int)x0f, y0 = (int)y0f;
    const int x1 = x0 + 1,  y1 = y0 + 1;

    const bool vx0 = (x0 >= 0) & (x0 <= Wx - 1);
    const bool vx1 = (x1 >= 0) & (x1 <= Wx - 1);
    const bool vy0 = (y0 >= 0) & (y0 <= Hx - 1);
    const bool vy1 = (y1 >= 0) & (y1 <= Hx - 1);
    const int cx0 = min(max(x0, 0), Wx - 1), cx1 = min(max(x1, 0), Wx - 1);
    const int cy0 = min(max(y0, 0), Hx - 1), cy1 = min(max(y1, 0), Hx - 1);

    const float w00 = (1.0f - wy1) * (1.0f - wx1) * ((vy0 & vx0) ? 1.f : 0.f);
    const float w01 = (1.0f - wy1) * wx1          * ((vy0 & vx1) ? 1.f : 0.f);
    const float w10 = wy1 * (1.0f - wx1)          * ((vy1 & vx0) ? 1.f : 0.f);
    const float w11 = wy1 * wx1                   * ((vy1 & vx1) ? 1.f : 0.f);

    // Paired-corner fetch: float2 at column cb covers {cb, cb+1} which always
    // contains {cx0, cx1} (interior; x0=255 -> both .y; x0=-1 -> both .x;
    // fully-OOB lanes have zero weights).
    const int  cb   = min(max(x0, 0), Wx - 2);
    const bool sel0 = (cx0 == cb);
    const bool sel1 = (cx1 == cb);
    const int  oT   = cy0 * Wx + cb;
    const int  oB   = cy1 * Wx + cb;

    const int c0 = chunk * CPT;
    const size_t cbase = (size_t)(b * Cx + c0) * HWx;
    const float* __restrict__ gb = gamma + cbase;
    const float* __restrict__ bb = beta  + cbase;
    const float* __restrict__ hb = h     + cbase + pix;
    float* __restrict__       ob = out   + cbase + pix;
    const float* __restrict__ stp = stats + 2 * (b * Cx + c0);
    const float onem = 1.0f - m;

    // ---- phase 1: issue ALL 40 loads (statically-indexed register arrays) ----
    f2u gT[CPT], gB[CPT], bT[CPT], bB[CPT];
    float hv[CPT];
    #pragma unroll
    for (int c = 0; c < CPT; ++c) {
        const size_t coff = (size_t)c * HWx;
        gT[c] = ld2u(gb + coff + oT);
        gB[c] = ld2u(gb + coff + oB);
        bT[c] = ld2u(bb + coff + oT);
        bB[c] = ld2u(bb + coff + oB);
        hv[c] = hb[coff];
    }

    // ---- phase 2: compute + store ----
    #pragma unroll
    for (int c = 0; c < CPT; ++c) {
        const float g00 = sel0 ? gT[c].x : gT[c].y, g01 = sel1 ? gT[c].x : gT[c].y;
        const float g10 = sel0 ? gB[c].x : gB[c].y, g11 = sel1 ? gB[c].x : gB[c].y;
        const float b00 = sel0 ? bT[c].x : bT[c].y, b01 = sel1 ? bT[c].x : bT[c].y;
        const float b10 = sel0 ? bB[c].x : bB[c].y, b11 = sel1 ? bB[c].x : bB[c].y;

        const float gw = w00 * g00 + w01 * g01 + w10 * g10 + w11 * g11;
        const float bw = w00 * b00 + w01 * b01 + w10 * b10 + w11 * b11;
        const float hn = (hv[c] - stp[2 * c]) * stp[2 * c + 1];
        ob[(size_t)c * HWx] = (gw * m + hv[c] * onem) * hn + bw;
    }
}

// ---------------------------------------------------------------------------
extern "C" void kernel_launch(void* const* d_in, const int* in_sizes, int n_in,
                              void* d_out, int out_size, void* d_ws, size_t ws_size,
                              hipStream_t stream) {
    const float* h     = (const float*)d_in[0];
    const float* gamma = (const float*)d_in[1];
    const float* beta  = (const float*)d_in[2];
    const float* flow  = (const float*)d_in[3];
    const float* mask  = (const float*)d_in[4];
    float* out   = (float*)d_out;
    float* stats = (float*)d_ws;   // 2 * B * C floats = 4 KiB

    in_stats<<<Bx * Cx, 512, 0, stream>>>(h, stats);
    fuse_kernel<<<NCHUNK * Bx * Hx, 256, 0, stream>>>(h, gamma, beta, flow, mask,
                                                      stats, out);
}

// Round 9
// 514.798 us; speedup vs baseline: 1.0028x; 1.0028x over previous
//
#include <hip/hip_runtime.h>

// Problem shape (fixed by reference setup_inputs): B=4, C=128, H=W=256, fp32.
constexpr int Bx = 4;
constexpr int Cx = 128;
constexpr int Hx = 256;
constexpr int Wx = 256;
constexpr int HWx = Hx * Wx;
constexpr int NCHUNK = 16;          // channel chunks
constexpr int CPT = Cx / NCHUNK;    // 8 channels per thread

// 8B load with only 4B alignment guaranteed (gfx950 handles unaligned dwordx2).
struct f2u { float x, y; } __attribute__((packed, aligned(4)));
__device__ __forceinline__ f2u ld2u(const float* p) {
    return *reinterpret_cast<const f2u*>(p);
}

// ---------------------------------------------------------------------------
// Kernel 1: per-(b,c) instance-norm statistics.
// stats interleaved: stats[2g] = mean, stats[2g+1] = rsqrt(var+eps)
// ---------------------------------------------------------------------------
__global__ __launch_bounds__(512) void in_stats(const float* __restrict__ h,
                                                float* __restrict__ stats) {
    const int g = blockIdx.x;   // b*C + c
    const int t = threadIdx.x;
    const float4* p = reinterpret_cast<const float4*>(h + (size_t)g * HWx);

    float4 s4 = {0.f, 0.f, 0.f, 0.f};
    float4 q4 = {0.f, 0.f, 0.f, 0.f};
    #pragma unroll 4
    for (int i = t; i < HWx / 4; i += 512) {
        float4 v = p[i];
        s4.x += v.x; s4.y += v.y; s4.z += v.z; s4.w += v.w;
        q4.x += v.x * v.x; q4.y += v.y * v.y;
        q4.z += v.z * v.z; q4.w += v.w * v.w;
    }
    float s = (s4.x + s4.y) + (s4.z + s4.w);
    float q = (q4.x + q4.y) + (q4.z + q4.w);

    for (int off = 32; off > 0; off >>= 1) {
        s += __shfl_down(s, off, 64);
        q += __shfl_down(q, off, 64);
    }
    __shared__ float rs[8], rq[8];
    const int wid = t >> 6;
    if ((t & 63) == 0) { rs[wid] = s; rq[wid] = q; }
    __syncthreads();
    if (t == 0) {
        float S = 0.f, Q = 0.f;
        #pragma unroll
        for (int i = 0; i < 8; ++i) { S += rs[i]; Q += rq[i]; }
        const float mean = S * (1.0f / HWx);
        const float var  = Q * (1.0f / HWx) - mean * mean;
        stats[2 * g]     = mean;
        stats[2 * g + 1] = rsqrtf(var + 1e-5f);
    }
}

// ---------------------------------------------------------------------------
// Kernel 2: fused warp(gamma), warp(beta), instance-norm apply, combine.
// MLP-forced, round 3 of the fight with the scheduler:
//  - __launch_bounds__(256, 4): waves/EU=4 -> VGPR cap 128 (R6/R7 evidence:
//    without this, clang's occupancy heuristic caps pressure at ~36 VGPR and
//    re-serializes ANY source-level pipeline/batch structure).
//  - asm "memory" fence between the 40-load issue phase and the compute
//    phase: loads cannot sink past it, staging registers must stay live.
//  VGPR ~100+ in the counter CSV is the proof this finally materialized.
// ---------------------------------------------------------------------------
__global__ __launch_bounds__(256, 4) void fuse_kernel(
    const float* __restrict__ h,
    const float* __restrict__ gamma,
    const float* __restrict__ beta,
    const float* __restrict__ flow,
    const float* __restrict__ mask,
    const float* __restrict__ stats,
    float* __restrict__ out)
{
    constexpr int NWG = NCHUNK * Bx * Hx;            // 16384, %8 == 0
    const int orig = blockIdx.x;
    const int bid  = (orig & 7) * (NWG / 8) + (orig >> 3);  // bijective XCD swizzle

    const int chunk = bid >> 10;        // / (Bx*Hx)
    const int rem   = bid & 1023;
    const int b     = rem >> 8;
    const int y     = rem & (Hx - 1);
    const int x     = threadIdx.x;
    const int pix   = (y << 8) | x;

    const float fx = flow[(size_t)b * 2 * HWx + pix];
    const float fy = flow[(size_t)b * 2 * HWx + HWx + pix];
    const float m  = mask[(size_t)b * HWx + pix];

    // Replicate the reference arithmetic exactly (order + divisions):
    const float xs = (float)x / 255.0f;
    const float ys = (float)y / 255.0f;
    const float sx = 2.0f * xs - 1.0f + 2.0f * fx / 256.0f;
    const float sy = 2.0f * ys - 1.0f + 2.0f * fy / 256.0f;
    const float ix = (sx + 1.0f) * 0.5f * 255.0f;
    const float iy = (sy + 1.0f) * 0.5f * 255.0f;

    const float x0f = floorf(ix);
    const float y0f = floorf(iy);
    const float wx1 = ix - x0f;
    const float wy1 = iy - y0f;
    const int x0 = (int)x0f, y0 = (int)y0f;
    const int x1 = x0 + 1,  y1 = y0 + 1;

    const bool vx0 = (x0 >= 0) & (x0 <= Wx - 1);
    const bool vx1 = (x1 >= 0) & (x1 <= Wx - 1);
    const bool vy0 = (y0 >= 0) & (y0 <= Hx - 1);
    const bool vy1 = (y1 >= 0) & (y1 <= Hx - 1);
    const int cx0 = min(max(x0, 0), Wx - 1), cx1 = min(max(x1, 0), Wx - 1);
    const int cy0 = min(max(y0, 0), Hx - 1), cy1 = min(max(y1, 0), Hx - 1);

    const float w00 = (1.0f - wy1) * (1.0f - wx1) * ((vy0 & vx0) ? 1.f : 0.f);
    const float w01 = (1.0f - wy1) * wx1          * ((vy0 & vx1) ? 1.f : 0.f);
    const float w10 = wy1 * (1.0f - wx1)          * ((vy1 & vx0) ? 1.f : 0.f);
    const float w11 = wy1 * wx1                   * ((vy1 & vx1) ? 1.f : 0.f);

    // Paired-corner fetch: float2 at column cb covers {cb, cb+1} which always
    // contains {cx0, cx1} (interior; x0=255 -> both .y; x0=-1 -> both .x;
    // fully-OOB lanes have zero weights).
    const int  cb   = min(max(x0, 0), Wx - 2);
    const bool sel0 = (cx0 == cb);
    const bool sel1 = (cx1 == cb);
    const int  oT   = cy0 * Wx + cb;
    const int  oB   = cy1 * Wx + cb;

    const int c0 = chunk * CPT;
    const size_t cbase = (size_t)(b * Cx + c0) * HWx;
    const float* __restrict__ gb = gamma + cbase;
    const float* __restrict__ bb = beta  + cbase;
    const float* __restrict__ hb = h     + cbase + pix;
    float* __restrict__       ob = out   + cbase + pix;
    const float* __restrict__ stp = stats + 2 * (b * Cx + c0);
    const float onem = 1.0f - m;

    // ---- phase 1: issue ALL 40 loads (statically-indexed register arrays) ----
    f2u gT[CPT], gB[CPT], bT[CPT], bB[CPT];
    float hv[CPT];
    #pragma unroll
    for (int c = 0; c < CPT; ++c) {
        const size_t coff = (size_t)c * HWx;
        gT[c] = ld2u(gb + coff + oT);
        gB[c] = ld2u(gb + coff + oB);
        bT[c] = ld2u(bb + coff + oT);
        bB[c] = ld2u(bb + coff + oB);
        hv[c] = hb[coff];
    }

    // Compiler fence: loads above cannot sink below (asm may write memory);
    // their 72 destination registers must be live across this point.
    asm volatile("" ::: "memory");

    // ---- phase 2: compute + store ----
    #pragma unroll
    for (int c = 0; c < CPT; ++c) {
        const float g00 = sel0 ? gT[c].x : gT[c].y, g01 = sel1 ? gT[c].x : gT[c].y;
        const float g10 = sel0 ? gB[c].x : gB[c].y, g11 = sel1 ? gB[c].x : gB[c].y;
        const float b00 = sel0 ? bT[c].x : bT[c].y, b01 = sel1 ? bT[c].x : bT[c].y;
        const float b10 = sel0 ? bB[c].x : bB[c].y, b11 = sel1 ? bB[c].x : bB[c].y;

        const float gw = w00 * g00 + w01 * g01 + w10 * g10 + w11 * g11;
        const float bw = w00 * b00 + w01 * b01 + w10 * b10 + w11 * b11;
        const float hn = (hv[c] - stp[2 * c]) * stp[2 * c + 1];
        ob[(size_t)c * HWx] = (gw * m + hv[c] * onem) * hn + bw;
    }
}

// ---------------------------------------------------------------------------
extern "C" void kernel_launch(void* const* d_in, const int* in_sizes, int n_in,
                              void* d_out, int out_size, void* d_ws, size_t ws_size,
                              hipStream_t stream) {
    const float* h     = (const float*)d_in[0];
    const float* gamma = (const float*)d_in[1];
    const float* beta  = (const float*)d_in[2];
    const float* flow  = (const float*)d_in[3];
    const float* mask  = (const float*)d_in[4];
    float* out   = (float*)d_out;
    float* stats = (float*)d_ws;   // 2 * B * C floats = 4 KiB

    in_stats<<<Bx * Cx, 512, 0, stream>>>(h, stats);
    fuse_kernel<<<NCHUNK * Bx * Hx, 256, 0, stream>>>(h, gamma, beta, flow, mask,
                                                      stats, out);
}

// Round 12
// 513.415 us; speedup vs baseline: 1.0055x; 1.0027x over previous
//
#include <hip/hip_runtime.h>

// Problem shape (fixed by reference setup_inputs): B=4, C=128, H=W=256, fp32.
constexpr int Bx = 4;
constexpr int Cx = 128;
constexpr int Hx = 256;
constexpr int Wx = 256;
constexpr int HWx = Hx * Wx;
constexpr int NCHUNK = 16;          // channel chunks
constexpr int CPT = Cx / NCHUNK;    // 8 channels per thread

// 8B value in a VGPR pair; loads need only 4B alignment (gfx950 handles
// unaligned 8B global loads).
typedef float vf2 __attribute__((ext_vector_type(2)));
struct f2w { vf2 v; } __attribute__((packed, aligned(4)));
__device__ __forceinline__ vf2 ld2u(const float* p) {
    return reinterpret_cast<const f2w*>(p)->v;
}

// ---------------------------------------------------------------------------
// Kernel 1: per-(b,c) instance-norm statistics.
// stats interleaved: stats[2g] = mean, stats[2g+1] = rsqrt(var+eps)
// ---------------------------------------------------------------------------
__global__ __launch_bounds__(512) void in_stats(const float* __restrict__ h,
                                                float* __restrict__ stats) {
    const int g = blockIdx.x;   // b*C + c
    const int t = threadIdx.x;
    const float4* p = reinterpret_cast<const float4*>(h + (size_t)g * HWx);

    float4 s4 = {0.f, 0.f, 0.f, 0.f};
    float4 q4 = {0.f, 0.f, 0.f, 0.f};
    #pragma unroll 4
    for (int i = t; i < HWx / 4; i += 512) {
        float4 v = p[i];
        s4.x += v.x; s4.y += v.y; s4.z += v.z; s4.w += v.w;
        q4.x += v.x * v.x; q4.y += v.y * v.y;
        q4.z += v.z * v.z; q4.w += v.w * v.w;
    }
    float s = (s4.x + s4.y) + (s4.z + s4.w);
    float q = (q4.x + q4.y) + (q4.z + q4.w);

    for (int off = 32; off > 0; off >>= 1) {
        s += __shfl_down(s, off, 64);
        q += __shfl_down(q, off, 64);
    }
    __shared__ float rs[8], rq[8];
    const int wid = t >> 6;
    if ((t & 63) == 0) { rs[wid] = s; rq[wid] = q; }
    __syncthreads();
    if (t == 0) {
        float S = 0.f, Q = 0.f;
        #pragma unroll
        for (int i = 0; i < 8; ++i) { S += rs[i]; Q += rq[i]; }
        const float mean = S * (1.0f / HWx);
        const float var  = Q * (1.0f / HWx) - mean * mean;
        stats[2 * g]     = mean;
        stats[2 * g + 1] = rsqrtf(var + 1e-5f);
    }
}

// ---------------------------------------------------------------------------
// Kernel 2: fused warp(gamma), warp(beta), instance-norm apply, combine.
// MLP forced via VALUE-fences (round 4 vs the scheduler):
//  R9 finding: asm "memory" clobber is dissolved by AA — loads through
//  __restrict__ (noalias) pointers legally cross a memory-clobber asm.
//  Fix: asm volatile with tied "+v" operands on the loaded VALUES. Loads
//  can't sink below (results are asm inputs); compute can't hoist above
//  (it consumes the asm OUTPUTS). Data edges beat alias analysis.
//  __launch_bounds__(256,4) keeps the 128-VGPR license. VGPR ~100 = proof.
// ---------------------------------------------------------------------------
__global__ __launch_bounds__(256, 4) void fuse_kernel(
    const float* __restrict__ h,
    const float* __restrict__ gamma,
    const float* __restrict__ beta,
    const float* __restrict__ flow,
    const float* __restrict__ mask,
    const float* __restrict__ stats,
    float* __restrict__ out)
{
    constexpr int NWG = NCHUNK * Bx * Hx;            // 16384, %8 == 0
    const int orig = blockIdx.x;
    const int bid  = (orig & 7) * (NWG / 8) + (orig >> 3);  // bijective XCD swizzle

    const int chunk = bid >> 10;        // / (Bx*Hx)
    const int rem   = bid & 1023;
    const int b     = rem >> 8;
    const int y     = rem & (Hx - 1);
    const int x     = threadIdx.x;
    const int pix   = (y << 8) | x;

    const float fx = flow[(size_t)b * 2 * HWx + pix];
    const float fy = flow[(size_t)b * 2 * HWx + HWx + pix];
    const float m  = mask[(size_t)b * HWx + pix];

    // Replicate the reference arithmetic exactly (order + divisions):
    const float xs = (float)x / 255.0f;
    const float ys = (float)y / 255.0f;
    const float sx = 2.0f * xs - 1.0f + 2.0f * fx / 256.0f;
    const float sy = 2.0f * ys - 1.0f + 2.0f * fy / 256.0f;
    const float ix = (sx + 1.0f) * 0.5f * 255.0f;
    const float iy = (sy + 1.0f) * 0.5f * 255.0f;

    const float x0f = floorf(ix);
    const float y0f = floorf(iy);
    const float wx1 = ix - x0f;
    const float wy1 = iy - y0f;
    const int x0 = (int)x0f, y0 = (int)y0f;
    const int x1 = x0 + 1,  y1 = y0 + 1;

    const bool vx0 = (x0 >= 0) & (x0 <= Wx - 1);
    const bool vx1 = (x1 >= 0) & (x1 <= Wx - 1);
    const bool vy0 = (y0 >= 0) & (y0 <= Hx - 1);
    const bool vy1 = (y1 >= 0) & (y1 <= Hx - 1);
    const int cx0 = min(max(x0, 0), Wx - 1), cx1 = min(max(x1, 0), Wx - 1);
    const int cy0 = min(max(y0, 0), Hx - 1), cy1 = min(max(y1, 0), Hx - 1);

    const float w00 = (1.0f - wy1) * (1.0f - wx1) * ((vy0 & vx0) ? 1.f : 0.f);
    const float w01 = (1.0f - wy1) * wx1          * ((vy0 & vx1) ? 1.f : 0.f);
    const float w10 = wy1 * (1.0f - wx1)          * ((vy1 & vx0) ? 1.f : 0.f);
    const float w11 = wy1 * wx1                   * ((vy1 & vx1) ? 1.f : 0.f);

    // Paired-corner fetch: float2 at column cb covers {cb, cb+1} which always
    // contains {cx0, cx1} (interior; x0=255 -> both .y; x0=-1 -> both .x;
    // fully-OOB lanes have zero weights).
    const int  cb   = min(max(x0, 0), Wx - 2);
    const bool sel0 = (cx0 == cb);
    const bool sel1 = (cx1 == cb);
    const int  oT   = cy0 * Wx + cb;
    const int  oB   = cy1 * Wx + cb;

    const int c0 = chunk * CPT;
    const size_t cbase = (size_t)(b * Cx + c0) * HWx;
    const float* __restrict__ gb = gamma + cbase;
    const float* __restrict__ bb = beta  + cbase;
    const float* __restrict__ hb = h     + cbase + pix;
    float* __restrict__       ob = out   + cbase + pix;
    const float* __restrict__ stp = stats + 2 * (b * Cx + c0);
    const float onem = 1.0f - m;

    // ---- phase 1: issue ALL 40 loads into statically-indexed registers ----
    vf2 gT[CPT], gB[CPT], bT[CPT], bB[CPT];
    float hv[CPT];
    #pragma unroll
    for (int c = 0; c < CPT; ++c) {
        const size_t coff = (size_t)c * HWx;
        gT[c] = ld2u(gb + coff + oT);
        gB[c] = ld2u(gb + coff + oB);
        bT[c] = ld2u(bb + coff + oT);
        bB[c] = ld2u(bb + coff + oB);
        hv[c] = hb[coff];
    }

    // ---- bidirectional VALUE fence: tied "+v" operands. AA-proof. ----
    asm volatile("" : "+v"(gT[0]), "+v"(gT[1]), "+v"(gT[2]), "+v"(gT[3]),
                      "+v"(gT[4]), "+v"(gT[5]), "+v"(gT[6]), "+v"(gT[7]));
    asm volatile("" : "+v"(gB[0]), "+v"(gB[1]), "+v"(gB[2]), "+v"(gB[3]),
                      "+v"(gB[4]), "+v"(gB[5]), "+v"(gB[6]), "+v"(gB[7]));
    asm volatile("" : "+v"(bT[0]), "+v"(bT[1]), "+v"(bT[2]), "+v"(bT[3]),
                      "+v"(bT[4]), "+v"(bT[5]), "+v"(bT[6]), "+v"(bT[7]));
    asm volatile("" : "+v"(bB[0]), "+v"(bB[1]), "+v"(bB[2]), "+v"(bB[3]),
                      "+v"(bB[4]), "+v"(bB[5]), "+v"(bB[6]), "+v"(bB[7]));
    asm volatile("" : "+v"(hv[0]), "+v"(hv[1]), "+v"(hv[2]), "+v"(hv[3]),
                      "+v"(hv[4]), "+v"(hv[5]), "+v"(hv[6]), "+v"(hv[7]));

    // ---- phase 2: compute + store ----
    #pragma unroll
    for (int c = 0; c < CPT; ++c) {
        const float g00 = sel0 ? gT[c].x : gT[c].y, g01 = sel1 ? gT[c].x : gT[c].y;
        const float g10 = sel0 ? gB[c].x : gB[c].y, g11 = sel1 ? gB[c].x : gB[c].y;
        const float b00 = sel0 ? bT[c].x : bT[c].y, b01 = sel1 ? bT[c].x : bT[c].y;
        const float b10 = sel0 ? bB[c].x : bB[c].y, b11 = sel1 ? bB[c].x : bB[c].y;

        const float gw = w00 * g00 + w01 * g01 + w10 * g10 + w11 * g11;
        const float bw = w00 * b00 + w01 * b01 + w10 * b10 + w11 * b11;
        const float hn = (hv[c] - stp[2 * c]) * stp[2 * c + 1];
        ob[(size_t)c * HWx] = (gw * m + hv[c] * onem) * hn + bw;
    }
}

// ---------------------------------------------------------------------------
extern "C" void kernel_launch(void* const* d_in, const int* in_sizes, int n_in,
                              void* d_out, int out_size, void* d_ws, size_t ws_size,
                              hipStream_t stream) {
    const float* h     = (const float*)d_in[0];
    const float* gamma = (const float*)d_in[1];
    const float* beta  = (const float*)d_in[2];
    const float* flow  = (const float*)d_in[3];
    const float* mask  = (const float*)d_in[4];
    float* out   = (float*)d_out;
    float* stats = (float*)d_ws;   // 2 * B * C floats = 4 KiB

    in_stats<<<Bx * Cx, 512, 0, stream>>>(h, stats);
    fuse_kernel<<<NCHUNK * Bx * Hx, 256, 0, stream>>>(h, gamma, beta, flow, mask,
                                                      stats, out);
}